// Round 6
// baseline (216.789 us; speedup 1.0000x reference)
//
#include <hip/hip_runtime.h>

// EdgeLoss: weighted BCE-with-logits mean over 32x1x768x1024 fp32 tensors.
// result = (neg_num * S_pos + pos_num * S_neg) / (pos_num + neg_num) / n
// S_pos = sum over t==1 of bce(x,1), S_neg = sum over t==0 of bce(x,0),
// bce(x,t) = max(x,0) - x*t + log(1+exp(-|x|)).
//
// R5 -> R6: three rounds of register-level MLP attempts all collapsed to
// VGPR<=24 / ~2 loads in flight (backend sinks loads to uses); 72-82 us
// regardless of structure, and even fully-L3-resident replays took 80 us
// -> latency-bound, not HBM-bound. Fix: global_load_lds async DMA (uses NO
// VGPRs, cannot be collapsed) into a WAVE-PRIVATE LDS double buffer. Each
// wave reads only its own staged tiles, so the loop needs no __syncthreads
// at all -- only a wave-local s_waitcnt vmcnt(2). Prefetch for iter k+1
// stays in flight across iter k's compute.

#define GRID1 2048
#define BLOCK 256

// s_waitcnt imm (gfx9 encoding): [3:0] vmcnt lo, [6:4] expcnt, [11:8] lgkmcnt,
// [15:14] vmcnt hi. Don't-care exp=7, lgkm=15.
#define WAITCNT_VM2 0x0F72   // vmcnt(2)
#define WAITCNT_VM0 0x0F70   // vmcnt(0)

__device__ __forceinline__ void dma16(const float4* g, float4* l) {
  __builtin_amdgcn_global_load_lds(
      (const __attribute__((address_space(1))) void*)g,
      (__attribute__((address_space(3))) void*)l, 16, 0, 0);
}

__device__ __forceinline__ void do_elem(float xv, float tv,
                                        float& cp, float& cn,
                                        float& sp, float& sn) {
  float a = fabsf(xv);
  float e = __expf(-a);                 // v_exp_f32
  float l = __logf(1.0f + e);           // v_log_f32
  float c = fmaxf(xv, 0.f) + l;         // softplus(x) = bce(t==0); bce(t==1)=c-x
  bool pos = (tv == 1.0f);
  bool neg = (tv == 0.0f);
  cp += pos ? 1.0f : 0.0f;
  cn += neg ? 1.0f : 0.0f;
  sp += pos ? (c - xv) : 0.0f;
  sn += neg ? c : 0.0f;
}

__device__ __forceinline__ void do_vec4(float4 xv, float4 tv,
                                        float& cp, float& cn,
                                        float& sp, float& sn) {
  do_elem(xv.x, tv.x, cp, cn, sp, sn);
  do_elem(xv.y, tv.y, cp, cn, sp, sn);
  do_elem(xv.z, tv.z, cp, cn, sp, sn);
  do_elem(xv.w, tv.w, cp, cn, sp, sn);
}

__global__ __launch_bounds__(BLOCK, 8) void edge_loss_stage1(
    const float* __restrict__ x, const float* __restrict__ t,
    float* __restrict__ partials, long long n) {
  // [buf][array(x=0,t=1)][thread] ; wave w owns threads w*64..w*64+63.
  // DMA dest must be wave-uniform base + lane*16: &lds[b][a][wave*64] is.
  __shared__ float4 lds[2][2][BLOCK];   // 16 KB/block -> 8 blocks/CU fits 128/160 KB

  long long idx0 = (long long)blockIdx.x * BLOCK + threadIdx.x;  // float4 idx
  long long S = (long long)gridDim.x * BLOCK;
  long long n4 = n >> 2;
  long long niter = n4 / S;            // iterations where every thread is valid

  int lane = threadIdx.x & 63;
  int wave = threadIdx.x >> 6;

  const float4* __restrict__ x4 = (const float4*)x;
  const float4* __restrict__ t4 = (const float4*)t;

  float cp = 0.f, cn = 0.f, sp = 0.f, sn = 0.f;

  float4* lx0 = &lds[0][0][wave * 64];
  float4* lt0 = &lds[0][1][wave * 64];
  float4* lx1 = &lds[1][0][wave * 64];
  float4* lt1 = &lds[1][1][wave * 64];

  long long g = idx0;
  if (niter > 0) {
    dma16(x4 + g, lx0);                 // stage iter 0 into buf 0
    dma16(t4 + g, lt0);
  }
  #pragma unroll 1
  for (long long k = 0; k < niter; ++k) {
    int cur = (int)(k & 1);
    if (k + 1 < niter) {
      long long gn = g + S;             // prefetch iter k+1 into other buf
      dma16(x4 + gn, cur ? lx0 : lx1);
      dma16(t4 + gn, cur ? lt0 : lt1);
      __builtin_amdgcn_s_waitcnt(WAITCNT_VM2);  // iter k's 2 DMAs done;
                                                // prefetch stays in flight
    } else {
      __builtin_amdgcn_s_waitcnt(WAITCNT_VM0);
    }
    __asm__ volatile("" ::: "memory");  // keep LDS reads below the waitcnt
    float4 xv = (cur ? lx1 : lx0)[lane];
    float4 tv = (cur ? lt1 : lt0)[lane];
    do_vec4(xv, tv, cp, cn, sp, sn);
    g += S;
  }
  // remainder float4 (threads past the last full grid-stride round)
  if (g < n4) {
    do_vec4(x4[g], t4[g], cp, cn, sp, sn);
  }
  // scalar tail (n not a multiple of 4)
  for (long long j = (n4 << 2) + idx0; j < n; j += S) {
    do_elem(x[j], t[j], cp, cn, sp, sn);
  }

  // wave-64 shuffle reduction
  #pragma unroll
  for (int off = 32; off > 0; off >>= 1) {
    cp += __shfl_down(cp, off, 64);
    cn += __shfl_down(cn, off, 64);
    sp += __shfl_down(sp, off, 64);
    sn += __shfl_down(sn, off, 64);
  }

  __shared__ float s_cp[4], s_cn[4], s_sp[4], s_sn[4];
  if (lane == 0) { s_cp[wave] = cp; s_cn[wave] = cn; s_sp[wave] = sp; s_sn[wave] = sn; }
  __syncthreads();
  if (threadIdx.x == 0) {
    float tcp = 0.f, tcn = 0.f, tsp = 0.f, tsn = 0.f;
    #pragma unroll
    for (int k = 0; k < 4; ++k) { tcp += s_cp[k]; tcn += s_cn[k]; tsp += s_sp[k]; tsn += s_sn[k]; }
    int G = gridDim.x;
    partials[0 * G + blockIdx.x] = tcp;   // pos count
    partials[1 * G + blockIdx.x] = tcn;   // neg count
    partials[2 * G + blockIdx.x] = tsp;   // sum_pos
    partials[3 * G + blockIdx.x] = tsn;   // sum_neg
  }
}

__global__ __launch_bounds__(BLOCK) void edge_loss_stage2(
    const float* __restrict__ partials, float* __restrict__ out,
    int G, double inv_n) {
  double acc[4] = {0.0, 0.0, 0.0, 0.0};
  for (int i = threadIdx.x; i < G; i += BLOCK) {
    #pragma unroll
    for (int c = 0; c < 4; ++c) acc[c] += (double)partials[c * G + i];
  }
  #pragma unroll
  for (int off = 32; off > 0; off >>= 1) {
    #pragma unroll
    for (int c = 0; c < 4; ++c) acc[c] += __shfl_down(acc[c], off, 64);
  }
  __shared__ double s_acc[4][4];
  int lane = threadIdx.x & 63;
  int wave = threadIdx.x >> 6;
  if (lane == 0) {
    #pragma unroll
    for (int c = 0; c < 4; ++c) s_acc[wave][c] = acc[c];
  }
  __syncthreads();
  if (threadIdx.x == 0) {
    double pos = 0, neg = 0, spos = 0, sneg = 0;
    #pragma unroll
    for (int w = 0; w < 4; ++w) {
      pos += s_acc[w][0]; neg += s_acc[w][1];
      spos += s_acc[w][2]; sneg += s_acc[w][3];
    }
    double s = pos + neg;
    out[0] = (float)((neg * spos + pos * sneg) / s * inv_n);
  }
}

extern "C" void kernel_launch(void* const* d_in, const int* in_sizes, int n_in,
                              void* d_out, int out_size, void* d_ws, size_t ws_size,
                              hipStream_t stream) {
  const float* x = (const float*)d_in[0];
  const float* t = (const float*)d_in[1];
  long long n = (long long)in_sizes[0];
  float* partials = (float*)d_ws;  // 4 * GRID1 floats = 32 KB, fully written

  edge_loss_stage1<<<GRID1, BLOCK, 0, stream>>>(x, t, partials, n);
  edge_loss_stage2<<<1, BLOCK, 0, stream>>>(partials, (float*)d_out,
                                            GRID1, 1.0 / (double)n);
}

// Round 8
// 197.883 us; speedup vs baseline: 1.0955x; 1.0955x over previous
//
#include <hip/hip_runtime.h>

// EdgeLoss: weighted BCE-with-logits mean over 32x1x768x1024 fp32 tensors.
// result = (neg_num * S_pos + pos_num * S_neg) / (pos_num + neg_num) / n
// S_pos = sum over t==1 of bce(x,1), S_neg = sum over t==0 of bce(x,0),
// bce(x,t) = max(x,0) - x*t + log(1+exp(-|x|)).
//
// R6 -> R8 (R7 was a compile fix): all four prior structures (reg-unroll,
// reg-prefetch, pinned batch, LDS-DMA double buffer) plateau at 72-82 us
// (~2.6 TB/s effective) -> not queue-depth-bound. Suspect: x and t are each
// exactly 96 MiB (3*2^25), so x[i] and t[i] share channel/L2-set/L3-set/
// DRAM-bank bits for every i (explains 50% L3 hit on a 201 MB working set
// and 1.28 TB/s HBM), and whole-grid-stride focuses all 256 CUs on one
// aliased 8 MB window pair (tiny active row set, 2x thrashed).
// Now: per-block CONTIGUOUS segments (2048 independent sequential streams
// spread over the full array -> max bank-level parallelism) + nontemporal
// loads (single-use data, evict-first). Nontemporal builtin requires a
// native ext_vector pointer, not HIP_vector_type -> floatx4 typedef.

#define GRID1 2048
#define BLOCK 256

typedef float floatx4 __attribute__((ext_vector_type(4)));

__device__ __forceinline__ void do_elem(float xv, float tv,
                                        float& cp, float& cn,
                                        float& sp, float& sn) {
  float a = fabsf(xv);
  float e = __expf(-a);                 // v_exp_f32
  float l = __logf(1.0f + e);           // v_log_f32
  float c = fmaxf(xv, 0.f) + l;         // softplus(x) = bce(t==0); bce(t==1)=c-x
  bool pos = (tv == 1.0f);
  bool neg = (tv == 0.0f);
  cp += pos ? 1.0f : 0.0f;
  cn += neg ? 1.0f : 0.0f;
  sp += pos ? (c - xv) : 0.0f;
  sn += neg ? c : 0.0f;
}

__device__ __forceinline__ void do_vec4(floatx4 xv, floatx4 tv,
                                        float& cp, float& cn,
                                        float& sp, float& sn) {
  do_elem(xv.x, tv.x, cp, cn, sp, sn);
  do_elem(xv.y, tv.y, cp, cn, sp, sn);
  do_elem(xv.z, tv.z, cp, cn, sp, sn);
  do_elem(xv.w, tv.w, cp, cn, sp, sn);
}

__global__ __launch_bounds__(BLOCK, 8) void edge_loss_stage1(
    const float* __restrict__ x, const float* __restrict__ t,
    float* __restrict__ partials, long long n) {
  long long n4 = n >> 2;
  // Contiguous per-block segment [beg, end) of float4 indices.
  long long per = (n4 + gridDim.x - 1) / gridDim.x;
  long long beg = (long long)blockIdx.x * per;
  long long end = beg + per < n4 ? beg + per : n4;

  const floatx4* __restrict__ x4 = (const floatx4*)x;
  const floatx4* __restrict__ t4 = (const floatx4*)t;

  float cp = 0.f, cn = 0.f, sp = 0.f, sn = 0.f;

  // Block streams sequentially through its private segment; each iteration
  // touches one contiguous 4 KB window per array. 2048 blocks = 2048
  // independent sequential DRAM streams.
  #pragma unroll 1
  for (long long i = beg + threadIdx.x; i < end; i += BLOCK) {
    floatx4 xv = __builtin_nontemporal_load(&x4[i]);
    floatx4 tv = __builtin_nontemporal_load(&t4[i]);
    do_vec4(xv, tv, cp, cn, sp, sn);
  }
  // scalar tail (n not a multiple of 4), grid-stride across all blocks
  for (long long j = (n4 << 2) + (long long)blockIdx.x * BLOCK + threadIdx.x;
       j < n; j += (long long)gridDim.x * BLOCK) {
    do_elem(x[j], t[j], cp, cn, sp, sn);
  }

  // wave-64 shuffle reduction
  #pragma unroll
  for (int off = 32; off > 0; off >>= 1) {
    cp += __shfl_down(cp, off, 64);
    cn += __shfl_down(cn, off, 64);
    sp += __shfl_down(sp, off, 64);
    sn += __shfl_down(sn, off, 64);
  }

  __shared__ float s_cp[4], s_cn[4], s_sp[4], s_sn[4];
  int lane = threadIdx.x & 63;
  int wave = threadIdx.x >> 6;
  if (lane == 0) { s_cp[wave] = cp; s_cn[wave] = cn; s_sp[wave] = sp; s_sn[wave] = sn; }
  __syncthreads();
  if (threadIdx.x == 0) {
    float tcp = 0.f, tcn = 0.f, tsp = 0.f, tsn = 0.f;
    #pragma unroll
    for (int k = 0; k < 4; ++k) { tcp += s_cp[k]; tcn += s_cn[k]; tsp += s_sp[k]; tsn += s_sn[k]; }
    int G = gridDim.x;
    partials[0 * G + blockIdx.x] = tcp;   // pos count
    partials[1 * G + blockIdx.x] = tcn;   // neg count
    partials[2 * G + blockIdx.x] = tsp;   // sum_pos
    partials[3 * G + blockIdx.x] = tsn;   // sum_neg
  }
}

__global__ __launch_bounds__(BLOCK) void edge_loss_stage2(
    const float* __restrict__ partials, float* __restrict__ out,
    int G, double inv_n) {
  double acc[4] = {0.0, 0.0, 0.0, 0.0};
  for (int i = threadIdx.x; i < G; i += BLOCK) {
    #pragma unroll
    for (int c = 0; c < 4; ++c) acc[c] += (double)partials[c * G + i];
  }
  #pragma unroll
  for (int off = 32; off > 0; off >>= 1) {
    #pragma unroll
    for (int c = 0; c < 4; ++c) acc[c] += __shfl_down(acc[c], off, 64);
  }
  __shared__ double s_acc[4][4];
  int lane = threadIdx.x & 63;
  int wave = threadIdx.x >> 6;
  if (lane == 0) {
    #pragma unroll
    for (int c = 0; c < 4; ++c) s_acc[wave][c] = acc[c];
  }
  __syncthreads();
  if (threadIdx.x == 0) {
    double pos = 0, neg = 0, spos = 0, sneg = 0;
    #pragma unroll
    for (int w = 0; w < 4; ++w) {
      pos += s_acc[w][0]; neg += s_acc[w][1];
      spos += s_acc[w][2]; sneg += s_acc[w][3];
    }
    double s = pos + neg;
    out[0] = (float)((neg * spos + pos * sneg) / s * inv_n);
  }
}

extern "C" void kernel_launch(void* const* d_in, const int* in_sizes, int n_in,
                              void* d_out, int out_size, void* d_ws, size_t ws_size,
                              hipStream_t stream) {
  const float* x = (const float*)d_in[0];
  const float* t = (const float*)d_in[1];
  long long n = (long long)in_sizes[0];
  float* partials = (float*)d_ws;  // 4 * GRID1 floats = 32 KB, fully written

  edge_loss_stage1<<<GRID1, BLOCK, 0, stream>>>(x, t, partials, n);
  edge_loss_stage2<<<1, BLOCK, 0, stream>>>(partials, (float*)d_out,
                                            GRID1, 1.0 / (double)n);
}